// Round 14
// baseline (155.017 us; speedup 1.0000x reference)
//
#include <hip/hip_runtime.h>
#include <hip/hip_bf16.h>
#include <cstdint>

constexpr int kNS = 4096;
constexpr int kNG = 20000;
constexpr int kE  = 131072;
constexpr int kNCAT = kNG + kNS;          // 24096
constexpr int kNB = (kNCAT + 255) / 256;  // 95 scan blocks
constexpr float kL2E = 1.4426950408889634f;

typedef __attribute__((ext_vector_type(8))) short short8;
typedef __attribute__((ext_vector_type(4))) float f32x4;
typedef __attribute__((ext_vector_type(2))) float f32x2;

__device__ __forceinline__ float elu_f(float v) { return v > 0.f ? v : expm1f(v); }

__device__ __forceinline__ unsigned short f2bf(float f) {
  union { float f; unsigned u; } v; v.f = f;
  unsigned r = v.u + 0x7FFF + ((v.u >> 16) & 1);
  return (unsigned short)(r >> 16);
}

__device__ __forceinline__ float bf2f(unsigned short u) {
  union { unsigned u; float f; } v; v.u = ((unsigned)u) << 16; return v.f;
}

// unpack 2 bf16 (packed in a dword) -> f32x2 {lo, hi}
__device__ __forceinline__ f32x2 bfp2(unsigned u) {
  union { unsigned u; float f; } lo, hi;
  lo.u = u << 16; hi.u = u & 0xffff0000u;
  return (f32x2){lo.f, hi.f};
}

// ================= zero kernel (deg|pval|pflag region + psrc pads) ====
__global__ __launch_bounds__(256) void zero_int(int* __restrict__ p, int n,
                                                int* __restrict__ padA,
                                                int* __restrict__ padB) {
  int i = blockIdx.x * 256 + threadIdx.x;
  if (i < n) p[i] = 0;
  if (blockIdx.x == 0 && threadIdx.x < 24) {
    padA[threadIdx.x] = 0;
    padB[threadIdx.x] = 0;
  }
}

// ================= prep: conversions / LDS-tiled W transpose / bias / histogram ========
__global__ __launch_bounds__(256) void prep(
    const float* __restrict__ xs, const float* __restrict__ xg,
    const float* __restrict__ Wl1_sg, const float* __restrict__ Wr1_gs,
    const float* __restrict__ sl1_W, const float* __restrict__ Wr1_sg,
    const float* __restrict__ Wl1_gs, const float* __restrict__ Wl3,
    const float* __restrict__ Wr3, const float* __restrict__ sl3_W,
    const float* __restrict__ bl1_sg, const float* __restrict__ br1_gs,
    const float* __restrict__ sl1_b, const float* __restrict__ br1_sg,
    const float* __restrict__ bl1_gs, const float* __restrict__ br3,
    const float* __restrict__ sl3_b,
    const int* __restrict__ sg_dst, const int* __restrict__ gs_dst,
    int* __restrict__ deg_g, int* __restrict__ deg_s,
    unsigned short* __restrict__ xs_bf, unsigned short* __restrict__ xg_bf,
    unsigned short* __restrict__ Wt1, unsigned short* __restrict__ Wt2,
    unsigned short* __restrict__ Wt3, unsigned short* __restrict__ Wt4,
    float* __restrict__ bc1, float* __restrict__ bc2, float* __restrict__ bc4) {
  __shared__ float tile[64][65];
  int bid = blockIdx.x, tid = threadIdx.x;
  if (bid < 1024) {
    int i = (bid * 256 + tid) * 4;
    float4 v = *(const float4*)&xs[i];
    ushort4 o = {f2bf(v.x), f2bf(v.y), f2bf(v.z), f2bf(v.w)};
    *(ushort4*)&xs_bf[i] = o;
    return;
  }
  bid -= 1024;
  if (bid < 5000) {
    int i = (bid * 256 + tid) * 4;
    float4 v = *(const float4*)&xg[i];
    ushort4 o = {f2bf(v.x), f2bf(v.y), f2bf(v.z), f2bf(v.w)};
    *(ushort4*)&xg_bf[i] = o;
    return;
  }
  bid -= 5000;
  auto wtile = [&](const float* W, unsigned short* Wt, int N, int b) {
    int ntn = N >> 6;
    int tn = b % ntn, tk = b / ntn;
    int c = tid & 63, rb = tid >> 6;
#pragma unroll
    for (int w = 0; w < 16; ++w) {
      int r = rb + w * 4;
      tile[r][c] = W[(size_t)(tk * 64 + r) * N + tn * 64 + c];
    }
    __syncthreads();
#pragma unroll
    for (int w = 0; w < 16; ++w) {
      int n = rb + w * 4;
      Wt[(size_t)(tn * 64 + n) * 256 + tk * 64 + c] = f2bf(tile[c][n]);
    }
  };
  if (bid < 36) {               // Wt1 = [Wl1_sg | Wr1_gs | sl1_W], N=576
    int ntn = 9, tn = bid % ntn, tk = bid / ntn;
    int c = tid & 63, rb = tid >> 6;
    int ncol = tn * 64;
#pragma unroll
    for (int w = 0; w < 16; ++w) {
      int r = rb + w * 4;
      int col = ncol + c;
      float v;
      if (col < 256) v = Wl1_sg[(size_t)(tk * 64 + r) * 256 + col];
      else if (col < 512) v = Wr1_gs[(size_t)(tk * 64 + r) * 256 + (col - 256)];
      else v = sl1_W[(size_t)(tk * 64 + r) * 64 + (col - 512)];
      tile[r][c] = v;
    }
    __syncthreads();
#pragma unroll
    for (int w = 0; w < 16; ++w) {
      int n = rb + w * 4;
      Wt1[(size_t)(ncol + n) * 256 + tk * 64 + c] = f2bf(tile[c][n]);
    }
    return;
  }
  bid -= 36;
  if (bid < 32) {               // Wt2 = [Wr1_sg | Wl1_gs], N=512
    int ntn = 8, tn = bid % ntn, tk = bid / ntn;
    int c = tid & 63, rb = tid >> 6;
    int ncol = tn * 64;
#pragma unroll
    for (int w = 0; w < 16; ++w) {
      int r = rb + w * 4;
      int col = ncol + c;
      float v = col < 256 ? Wr1_sg[(size_t)(tk * 64 + r) * 256 + col]
                          : Wl1_gs[(size_t)(tk * 64 + r) * 256 + (col - 256)];
      tile[r][c] = v;
    }
    __syncthreads();
#pragma unroll
    for (int w = 0; w < 16; ++w) {
      int n = rb + w * 4;
      Wt2[(size_t)(ncol + n) * 256 + tk * 64 + c] = f2bf(tile[c][n]);
    }
    return;
  }
  bid -= 32;
  if (bid < 32) { wtile(Wl3, Wt3, 512, bid); return; }
  bid -= 32;
  if (bid < 40) {               // Wt4 = [Wr3 | sl3_W], N=640
    int ntn = 10, tn = bid % ntn, tk = bid / ntn;
    int c = tid & 63, rb = tid >> 6;
    int ncol = tn * 64;
#pragma unroll
    for (int w = 0; w < 16; ++w) {
      int r = rb + w * 4;
      int col = ncol + c;
      float v = col < 512 ? Wr3[(size_t)(tk * 64 + r) * 512 + col]
                          : sl3_W[(size_t)(tk * 64 + r) * 128 + (col - 512)];
      tile[r][c] = v;
    }
    __syncthreads();
#pragma unroll
    for (int w = 0; w < 16; ++w) {
      int n = rb + w * 4;
      Wt4[(size_t)(ncol + n) * 256 + tk * 64 + c] = f2bf(tile[c][n]);
    }
    return;
  }
  bid -= 40;
  if (bid < 7) {
    int j = bid * 256 + tid;
    if (j < 256) bc1[j] = bl1_sg[j];
    else if (j < 512) bc1[j] = br1_gs[j - 256];
    else if (j < 576) bc1[j] = sl1_b[j - 512];
    else if (j < 832) bc2[j - 576] = br1_sg[j - 576];
    else if (j < 1088) bc2[j - 576] = bl1_gs[j - 832];
    else if (j < 1600) bc4[j - 1088] = br3[j - 1088];
    else if (j < 1728) bc4[j - 1088] = sl3_b[j - 1600];
    return;
  }
  bid -= 7;
  int i = bid * 256 + tid;
  if (i < kE) atomicAdd(&deg_g[sg_dst[i]], 1);
  else atomicAdd(&deg_s[gs_dst[i - kE]], 1);
}

// ================= single-dispatch scan with decoupled lookback =================
__global__ __launch_bounds__(256) void scan_fused(
    int* __restrict__ deg, int* __restrict__ rp_g, int* __restrict__ rp_s,
    int* __restrict__ pval, int* __restrict__ pflag) {
  int b = blockIdx.x, t = threadIdx.x;
  int i = b * 256 + t;
  int v = i < kNCAT ? deg[i] : 0;
  __shared__ int s[256];
  s[t] = v;
  __syncthreads();
  for (int ofs = 1; ofs < 256; ofs <<= 1) {
    int add = t >= ofs ? s[t - ofs] : 0;
    __syncthreads();
    s[t] += add;
    __syncthreads();
  }
  if (t == 255) {
    atomicExch(&pval[b], s[255]);
    __threadfence();
    atomicExch(&pflag[b], 1);
  }
  int pre = 0;
  if (t < b) {
    while (atomicAdd(&pflag[t], 0) == 0) {}
    pre = atomicAdd(&pval[t], 0);
  }
  pre += __shfl_xor(pre, 1);  pre += __shfl_xor(pre, 2);
  pre += __shfl_xor(pre, 4);  pre += __shfl_xor(pre, 8);
  pre += __shfl_xor(pre, 16); pre += __shfl_xor(pre, 32);
  __shared__ int ws4[4];
  if ((t & 63) == 0) ws4[t >> 6] = pre;
  __syncthreads();
  int prefix = ws4[0] + ws4[1] + ws4[2] + ws4[3];
  int ex = prefix + s[t] - v;
  if (i < kNG) { rp_g[i] = ex; deg[i] = 0; }
  else if (i < kNCAT) { rp_s[i - kNG] = ex - kE; deg[i] = 0; }
  if (b == 0 && t == 0) { rp_g[kNG] = kE; rp_s[kNS] = kE; }
}

// ================= MFMA GEMM body (128x64 tile, BK=32, K=256) =================
__device__ __forceinline__ void gemm_body(
    const unsigned short* __restrict__ A, const unsigned short* __restrict__ Bt,
    const float* __restrict__ bias, unsigned short* __restrict__ Cb,
    int M, int N, int bx, int by) {
  __shared__ alignas(16) unsigned short As[128 * 32];
  __shared__ alignas(16) unsigned short Bs[64 * 32];
  const int tid = threadIdx.x;
  const int wave = tid >> 6, lane = tid & 63;
  const int brow = by * 128, bcol = bx * 64;
  const int wrow = (wave >> 1) * 64, wcol = (wave & 1) * 32;
  const int la = lane & 15, lk = (lane >> 4) * 8;
  f32x4 acc[4][2] = {};
  for (int k0 = 0; k0 < 256; k0 += 32) {
#pragma unroll
    for (int c = 0; c < 2; ++c) {
      int seg = wave * 128 + c * 64 + lane;
      int row = seg >> 2, ks = (seg & 3) * 8;
      int grow = brow + row; if (grow > M - 1) grow = M - 1;
      const unsigned short* g = A + (size_t)grow * 256 + k0 + ks;
      __builtin_amdgcn_global_load_lds(
          (const __attribute__((address_space(1))) unsigned*)g,
          (__attribute__((address_space(3))) unsigned*)&As[(wave * 128 + c * 64) * 8],
          16, 0, 0);
    }
    {
      int seg = wave * 64 + lane;
      int row = seg >> 2, ks = (seg & 3) * 8;
      const unsigned short* g = Bt + (size_t)(bcol + row) * 256 + k0 + ks;
      __builtin_amdgcn_global_load_lds(
          (const __attribute__((address_space(1))) unsigned*)g,
          (__attribute__((address_space(3))) unsigned*)&Bs[(wave * 64) * 8],
          16, 0, 0);
    }
    __syncthreads();
    short8 bfr[2];
#pragma unroll
    for (int ni = 0; ni < 2; ++ni)
      bfr[ni] = *(const short8*)&Bs[(wcol + ni * 16 + la) * 32 + lk];
#pragma unroll
    for (int mi = 0; mi < 4; ++mi) {
      short8 af = *(const short8*)&As[(wrow + mi * 16 + la) * 32 + lk];
#pragma unroll
      for (int ni = 0; ni < 2; ++ni)
        acc[mi][ni] = __builtin_amdgcn_mfma_f32_16x16x32_bf16(af, bfr[ni], acc[mi][ni], 0, 0, 0);
    }
    __syncthreads();
  }
  const int r0 = (lane >> 4) * 4;
#pragma unroll
  for (int mi = 0; mi < 4; ++mi) {
#pragma unroll
    for (int r = 0; r < 4; ++r) {
      int row = brow + wrow + mi * 16 + r0 + r;
      if (row >= M) continue;
#pragma unroll
      for (int ni = 0; ni < 2; ++ni) {
        int col = bcol + wcol + ni * 16 + la;
        Cb[(size_t)row * N + col] = f2bf(acc[mi][ni][r] + bias[col]);
      }
    }
  }
}

// XCD-aware tile decode (T1): contiguous by-range per XCD so A-panels live in ONE L2.
__device__ __forceinline__ void gemm_swz(
    const unsigned short* A, const unsigned short* Bt, const float* bias,
    unsigned short* Cb, int M, int N, int flat, int nbx, int rows_per_xcd) {
  int x = flat & 7, k = flat >> 3;
  int by = x * rows_per_xcd + k / nbx;
  int bx = k % nbx;
  if (by * 128 >= M) return;
  gemm_body(A, Bt, bias, Cb, M, N, bx, by);
}

// CSR perm-build region FIRST (overlaps GEMM; tail = uniform GEMM tiles), then 2 GEMMs.
__global__ __launch_bounds__(256) void gemm_build(
    int nbuild,
    const unsigned short* __restrict__ A0, const unsigned short* __restrict__ B0,
    const float* __restrict__ b0, unsigned short* __restrict__ C0, int M0, int N0,
    int nb0, int nbx0, int rpx0,
    const unsigned short* __restrict__ A1, const unsigned short* __restrict__ B1,
    const float* __restrict__ b1, unsigned short* __restrict__ C1, int M1, int N1,
    int nbx1, int rpx1,
    const int* __restrict__ sgd, const int* __restrict__ sgs,
    const int* __restrict__ rpg, int* __restrict__ curg, int* __restrict__ psg,
    const int* __restrict__ gsd, const int* __restrict__ gss,
    const int* __restrict__ rps, int* __restrict__ curs, int* __restrict__ pss) {
  int flat = blockIdx.x;
  if (flat < nbuild) {
    int i = flat * 256 + threadIdx.x;
    if (i < kE) {
      int d = sgd[i];
      psg[rpg[d] + atomicAdd(&curg[d], 1)] = sgs[i] * 576;   // stage-1 xl ld = 576
    } else {
      i -= kE;
      int d = gsd[i];
      pss[rps[d] + atomicAdd(&curs[d], 1)] = gss[i] * 512;   // stage-2/3 xl ld = 512
    }
    return;
  }
  flat -= nbuild;
  if (flat < nb0) {
    gemm_swz(A0, B0, b0, C0, M0, N0, flat, nbx0, rpx0);
    return;
  }
  flat -= nb0;
  gemm_swz(A1, B1, b1, C1, M1, N1, flat, nbx1, rpx1);
}

// ====== fused GATv2, C=64, no-max softmax, 3-stage pipeline (idx+2 / rows+1 / compute) =
// psrc padded with >=24 zeros; over-reads land in later dsts' valid offsets or the pad.
template <bool SPLIT, bool ADDSL>
__device__ __forceinline__ void gat64_body(
    const unsigned short* __restrict__ xl,
    const unsigned short* __restrict__ xr, int ldr,
    const float* __restrict__ att,
    const int* __restrict__ psrc, const int* __restrict__ rp,
    const float* __restrict__ bias,
    const unsigned short* __restrict__ sl, int ldsl,
    unsigned short* __restrict__ out, int N, int rbid) {
  int tid = threadIdx.x;
  int cl = tid & 31;
  int d, sub;
  if (SPLIT) { d = rbid * 4 + (tid >> 6); sub = (tid >> 5) & 1; }
  else       { d = rbid * 8 + (tid >> 5); sub = 0; }
  if (d >= N) return;
  const unsigned short* xlb = xl + cl * 8;
  f32x2 xr2[4], at2[4];
  {
    const uint4 xu = *(const uint4*)&xr[(size_t)d * ldr + cl * 8];
    xr2[0] = bfp2(xu.x); xr2[1] = bfp2(xu.y); xr2[2] = bfp2(xu.z); xr2[3] = bfp2(xu.w);
    float4 a0 = *(const float4*)&att[cl * 8];
    float4 a1 = *(const float4*)&att[cl * 8 + 4];
    at2[0] = (f32x2){a0.x, a0.y} * kL2E; at2[1] = (f32x2){a0.z, a0.w} * kL2E;
    at2[2] = (f32x2){a1.x, a1.y} * kL2E; at2[3] = (f32x2){a1.z, a1.w} * kL2E;
  }
  float l = 0.f;
  f32x2 acc2[4] = {};
  int i0 = rp[d], i1 = rp[d + 1];
  constexpr int STRIDE = SPLIT ? 8 : 4;
  int i = SPLIT ? i0 + sub * 4 : i0;
  // pipeline prologue: rows for round 0, indices for round 1
  int o0 = psrc[i], o1 = psrc[i + 1], o2 = psrc[i + 2], o3 = psrc[i + 3];
  uint4 xu0 = *(const uint4*)&xlb[o0];
  uint4 xu1 = *(const uint4*)&xlb[o1];
  uint4 xu2 = *(const uint4*)&xlb[o2];
  uint4 xu3 = *(const uint4*)&xlb[o3];
  o0 = psrc[i + STRIDE];     o1 = psrc[i + STRIDE + 1];
  o2 = psrc[i + STRIDE + 2]; o3 = psrc[i + STRIDE + 3];
  for (; i < i1; i += STRIDE) {
    // issue next-round row gathers (indices already resident)
    uint4 yu0 = *(const uint4*)&xlb[o0];
    uint4 yu1 = *(const uint4*)&xlb[o1];
    uint4 yu2 = *(const uint4*)&xlb[o2];
    uint4 yu3 = *(const uint4*)&xlb[o3];
    // load indices for round +2
    int nx = i + 2 * STRIDE;
    o0 = psrc[nx]; o1 = psrc[nx + 1]; o2 = psrc[nx + 2]; o3 = psrc[nx + 3];
    // process current rows
    f32x2 xf[4][4];
    xf[0][0] = bfp2(xu0.x); xf[0][1] = bfp2(xu0.y); xf[0][2] = bfp2(xu0.z); xf[0][3] = bfp2(xu0.w);
    xf[1][0] = bfp2(xu1.x); xf[1][1] = bfp2(xu1.y); xf[1][2] = bfp2(xu1.z); xf[1][3] = bfp2(xu1.w);
    xf[2][0] = bfp2(xu2.x); xf[2][1] = bfp2(xu2.y); xf[2][2] = bfp2(xu2.z); xf[2][3] = bfp2(xu2.w);
    xf[3][0] = bfp2(xu3.x); xf[3][1] = bfp2(xu3.y); xf[3][2] = bfp2(xu3.z); xf[3][3] = bfp2(xu3.w);
    float dt[4];
#pragma unroll
    for (int b = 0; b < 4; ++b) {
      f32x2 d2 = {0.f, 0.f};
#pragma unroll
      for (int p = 0; p < 4; ++p) {
        f32x2 v = xf[b][p] + xr2[p];
        f32x2 lk = __builtin_elementwise_max(v, v * 0.2f);
        d2 = __builtin_elementwise_fma(lk, at2[p], d2);
      }
      float dd = d2.x + d2.y;
      dd += __shfl_xor(dd, 1);
      dd += __shfl_xor(dd, 2);
      dd += __shfl_xor(dd, 4);   // 8-lane head reduce
      dt[b] = dd;
    }
    float w0 = __builtin_amdgcn_exp2f(dt[0]);
    float w1 = (i + 1 < i1) ? __builtin_amdgcn_exp2f(dt[1]) : 0.f;
    float w2 = (i + 2 < i1) ? __builtin_amdgcn_exp2f(dt[2]) : 0.f;
    float w3 = (i + 3 < i1) ? __builtin_amdgcn_exp2f(dt[3]) : 0.f;
    l += (w0 + w1) + (w2 + w3);
#pragma unroll
    for (int p = 0; p < 4; ++p) {
      acc2[p] = __builtin_elementwise_fma(xf[0][p], (f32x2){w0, w0}, acc2[p]);
      acc2[p] = __builtin_elementwise_fma(xf[1][p], (f32x2){w1, w1}, acc2[p]);
      acc2[p] = __builtin_elementwise_fma(xf[2][p], (f32x2){w2, w2}, acc2[p]);
      acc2[p] = __builtin_elementwise_fma(xf[3][p], (f32x2){w3, w3}, acc2[p]);
    }
    xu0 = yu0; xu1 = yu1; xu2 = yu2; xu3 = yu3;
  }
  if (SPLIT) {
    l += __shfl_xor(l, 32);
#pragma unroll
    for (int p = 0; p < 4; ++p) {
      acc2[p].x += __shfl_xor(acc2[p].x, 32);
      acc2[p].y += __shfl_xor(acc2[p].y, 32);
    }
    if (sub != 0) return;
  }
  float dinv = __builtin_amdgcn_rcpf(l + 1e-16f);
  short8 o;
#pragma unroll
  for (int p = 0; p < 4; ++p) {
    int c = cl * 8 + p * 2;
    float v0 = acc2[p].x * dinv + bias[c];
    float v1 = acc2[p].y * dinv + bias[c + 1];
    if (ADDSL) {
      v0 += bf2f(sl[(size_t)d * ldsl + (c & 63)]);
      v1 += bf2f(sl[(size_t)d * ldsl + ((c + 1) & 63)]);
    }
    o[p * 2]     = (short)f2bf(elu_f(v0));
    o[p * 2 + 1] = (short)f2bf(elu_f(v1));
  }
  *(short8*)&out[(size_t)d * 256 + cl * 8] = o;
}

// stage2 (split, heavy) FIRST so the dispatch tail drains on cheap stage-1 blocks
__global__ __launch_bounds__(256) void gat12(
    const unsigned short* __restrict__ xlA,
    const unsigned short* __restrict__ xrA, int ldrA,
    const float* __restrict__ attA, const int* __restrict__ psA,
    const int* __restrict__ rpA, const float* __restrict__ biasA,
    unsigned short* __restrict__ outA, int NA,
    const unsigned short* __restrict__ xlB,
    const unsigned short* __restrict__ xrB, int ldrB,
    const float* __restrict__ attB, const int* __restrict__ psB,
    const int* __restrict__ rpB, const float* __restrict__ biasB,
    const unsigned short* __restrict__ slB, int ldslB,
    unsigned short* __restrict__ outB, int NB, int nbB) {
  int bid = blockIdx.x;
  if (bid < nbB)
    gat64_body<true, true>(xlB, xrB, ldrB, attB, psB, rpB, biasB,
                           slB, ldslB, outB, NB, bid);
  else
    gat64_body<false, false>(xlA, xrA, ldrA, attA, psA, rpA, biasA,
                             nullptr, 0, outA, NA, bid - nbB);
}

// ====== stage-3 GAT, C=128: 2 waves/dst, 3-stage pipeline, LDS add-merge, head-mean ====
__global__ __launch_bounds__(256) void gat3(
    const unsigned short* __restrict__ xl,   // [NG,512] (offsets pre-scaled by 512)
    const unsigned short* __restrict__ xr,   // cat4 [NS,640], cols 0..511
    const float* __restrict__ att,
    const int* __restrict__ psrc, const int* __restrict__ rp,
    const float* __restrict__ bias,
    const unsigned short* __restrict__ sl,   // cat4 cols 512..639
    float* __restrict__ out) {
  __shared__ float sm_acc[2][64][8];
  __shared__ float sm_l[2][64];
  int w = threadIdx.x >> 6, lane = threadIdx.x & 63;
  int p = w >> 1, wp = w & 1;
  int d = blockIdx.x * 2 + p;
  const unsigned short* xlb = xl + lane * 8;
  f32x2 xr2[4], at2[4];
  {
    const uint4 xu = *(const uint4*)&xr[(size_t)d * 640 + lane * 8];
    xr2[0] = bfp2(xu.x); xr2[1] = bfp2(xu.y); xr2[2] = bfp2(xu.z); xr2[3] = bfp2(xu.w);
    float4 a0 = *(const float4*)&att[lane * 8];
    float4 a1 = *(const float4*)&att[lane * 8 + 4];
    at2[0] = (f32x2){a0.x, a0.y} * kL2E; at2[1] = (f32x2){a0.z, a0.w} * kL2E;
    at2[2] = (f32x2){a1.x, a1.y} * kL2E; at2[3] = (f32x2){a1.z, a1.w} * kL2E;
  }
  float l = 0.f;
  f32x2 acc2[4] = {};
  int i0 = rp[d], i1 = rp[d + 1];
  int i = i0 + wp * 4;
  int o0 = psrc[i], o1 = psrc[i + 1], o2 = psrc[i + 2], o3 = psrc[i + 3];
  uint4 xu0 = *(const uint4*)&xlb[o0];
  uint4 xu1 = *(const uint4*)&xlb[o1];
  uint4 xu2 = *(const uint4*)&xlb[o2];
  uint4 xu3 = *(const uint4*)&xlb[o3];
  o0 = psrc[i + 8]; o1 = psrc[i + 9]; o2 = psrc[i + 10]; o3 = psrc[i + 11];
  for (; i < i1; i += 8) {
    uint4 yu0 = *(const uint4*)&xlb[o0];
    uint4 yu1 = *(const uint4*)&xlb[o1];
    uint4 yu2 = *(const uint4*)&xlb[o2];
    uint4 yu3 = *(const uint4*)&xlb[o3];
    int nx = i + 16;
    o0 = psrc[nx]; o1 = psrc[nx + 1]; o2 = psrc[nx + 2]; o3 = psrc[nx + 3];
    f32x2 xf[4][4];
    xf[0][0] = bfp2(xu0.x); xf[0][1] = bfp2(xu0.y); xf[0][2] = bfp2(xu0.z); xf[0][3] = bfp2(xu0.w);
    xf[1][0] = bfp2(xu1.x); xf[1][1] = bfp2(xu1.y); xf[1][2] = bfp2(xu1.z); xf[1][3] = bfp2(xu1.w);
    xf[2][0] = bfp2(xu2.x); xf[2][1] = bfp2(xu2.y); xf[2][2] = bfp2(xu2.z); xf[2][3] = bfp2(xu2.w);
    xf[3][0] = bfp2(xu3.x); xf[3][1] = bfp2(xu3.y); xf[3][2] = bfp2(xu3.z); xf[3][3] = bfp2(xu3.w);
    float dt[4];
#pragma unroll
    for (int b = 0; b < 4; ++b) {
      f32x2 d2 = {0.f, 0.f};
#pragma unroll
      for (int q = 0; q < 4; ++q) {
        f32x2 v = xf[b][q] + xr2[q];
        f32x2 lk = __builtin_elementwise_max(v, v * 0.2f);
        d2 = __builtin_elementwise_fma(lk, at2[q], d2);
      }
      float dd = d2.x + d2.y;
      dd += __shfl_xor(dd, 1);
      dd += __shfl_xor(dd, 2);
      dd += __shfl_xor(dd, 4);
      dd += __shfl_xor(dd, 8);   // 16-lane head reduce (C=128)
      dt[b] = dd;
    }
    float w0 = __builtin_amdgcn_exp2f(dt[0]);
    float w1 = (i + 1 < i1) ? __builtin_amdgcn_exp2f(dt[1]) : 0.f;
    float w2 = (i + 2 < i1) ? __builtin_amdgcn_exp2f(dt[2]) : 0.f;
    float w3 = (i + 3 < i1) ? __builtin_amdgcn_exp2f(dt[3]) : 0.f;
    l += (w0 + w1) + (w2 + w3);
#pragma unroll
    for (int q = 0; q < 4; ++q) {
      acc2[q] = __builtin_elementwise_fma(xf[0][q], (f32x2){w0, w0}, acc2[q]);
      acc2[q] = __builtin_elementwise_fma(xf[1][q], (f32x2){w1, w1}, acc2[q]);
      acc2[q] = __builtin_elementwise_fma(xf[2][q], (f32x2){w2, w2}, acc2[q]);
      acc2[q] = __builtin_elementwise_fma(xf[3][q], (f32x2){w3, w3}, acc2[q]);
    }
    xu0 = yu0; xu1 = yu1; xu2 = yu2; xu3 = yu3;
  }
  if (wp == 1) {
#pragma unroll
    for (int q = 0; q < 4; ++q) {
      sm_acc[p][lane][q * 2]     = acc2[q].x;
      sm_acc[p][lane][q * 2 + 1] = acc2[q].y;
    }
    sm_l[p][lane] = l;
  }
  __syncthreads();
  if (wp == 0) {
    l += sm_l[p][lane];
    float dinv = __builtin_amdgcn_rcpf(l + 1e-16f);
    float r[8];
#pragma unroll
    for (int q = 0; q < 4; ++q) {
      r[q * 2]     = (acc2[q].x + sm_acc[p][lane][q * 2]) * dinv;
      r[q * 2 + 1] = (acc2[q].y + sm_acc[p][lane][q * 2 + 1]) * dinv;
    }
#pragma unroll
    for (int j = 0; j < 8; ++j) {
      r[j] += __shfl_xor(r[j], 16);
      r[j] += __shfl_xor(r[j], 32);
    }
    if (lane < 16) {
#pragma unroll
      for (int j = 0; j < 8; ++j) {
        int c = lane * 8 + j;
        out[(size_t)d * 128 + c] =
            elu_f(0.25f * r[j] + bias[c] + bf2f(sl[(size_t)d * 640 + c]));
      }
    }
  }
}

extern "C" void kernel_launch(void* const* d_in, const int* in_sizes, int n_in,
                              void* d_out, int out_size, void* d_ws, size_t ws_size,
                              hipStream_t stream) {
  const float* x_sample = (const float*)d_in[0];
  const float* x_gene   = (const float*)d_in[1];
  const int* sg_src = (const int*)d_in[2];
  const int* sg_dst = (const int*)d_in[3];
  const int* gs_src = (const int*)d_in[4];
  const int* gs_dst = (const int*)d_in[5];
  const float* Wl1_sg = (const float*)d_in[6];
  const float* bl1_sg = (const float*)d_in[7];
  const float* Wr1_sg = (const float*)d_in[8];
  const float* br1_sg = (const float*)d_in[9];
  const float* att1_sg = (const float*)d_in[10];
  const float* bias1_sg = (const float*)d_in[11];
  const float* Wl1_gs = (const float*)d_in[12];
  const float* bl1_gs = (const float*)d_in[13];
  const float* Wr1_gs = (const float*)d_in[14];
  const float* br1_gs = (const float*)d_in[15];
  const float* att1_gs = (const float*)d_in[16];
  const float* bias1_gs = (const float*)d_in[17];
  const float* Wl3 = (const float*)d_in[18];
  const float* bl3 = (const float*)d_in[19];
  const float* Wr3 = (const float*)d_in[20];
  const float* br3 = (const float*)d_in[21];
  const float* att3 = (const float*)d_in[22];
  const float* bias3 = (const float*)d_in[23];
  const float* sl1_W = (const float*)d_in[24];
  const float* sl1_b = (const float*)d_in[25];
  const float* sl3_W = (const float*)d_in[26];
  const float* sl3_b = (const float*)d_in[27];

  float* ws = (float*)d_ws;
  size_t off = 0;
  auto alloc = [&](size_t n) { float* p = ws + off; off += n; return p; };
  float* bc1 = alloc(576);
  float* bc2 = alloc(512);
  float* bc4 = alloc(640);
  unsigned short* cat1 = (unsigned short*)alloc((size_t)kNS * 576 / 2);  // xl_sg|xr_gs|sl1o
  unsigned short* cat2 = (unsigned short*)alloc((size_t)kNG * 512 / 2);  // xr_sg|xl_gs
  unsigned short* xl3  = (unsigned short*)alloc((size_t)kNG * 512 / 2);
  unsigned short* cat4 = (unsigned short*)alloc((size_t)kNS * 640 / 2);  // xr3|sl3o
  unsigned short* xs_bf  = (unsigned short*)alloc((size_t)kNS * 256 / 2);
  unsigned short* xg_bf  = (unsigned short*)alloc((size_t)kNG * 256 / 2);
  unsigned short* xg1_bf = (unsigned short*)alloc((size_t)kNG * 256 / 2);
  unsigned short* xs1_bf = (unsigned short*)alloc((size_t)kNS * 256 / 2);
  unsigned short* Wt1 = (unsigned short*)alloc(576 * 256 / 2);
  unsigned short* Wt2 = (unsigned short*)alloc(512 * 256 / 2);
  unsigned short* Wt3 = (unsigned short*)alloc(512 * 256 / 2);
  unsigned short* Wt4 = (unsigned short*)alloc(640 * 256 / 2);
  int* deg_g  = (int*)alloc(kNG);   // deg_g|deg_s|pval|pflag contiguous for one zero pass
  int* deg_s  = (int*)alloc(kNS);
  int* pval   = (int*)alloc(128);
  int* pflag  = (int*)alloc(128);
  int* rp_g   = (int*)alloc(kNG + 1);
  int* rp_s   = (int*)alloc(kNS + 1);
  int* psrc_g = (int*)alloc(kE + 24);  // +24 pad (zeroed) for 2-round prefetch over-reads
  int* psrc_s = (int*)alloc(kE + 24);

  zero_int<<<(kNCAT + 256 + 255) / 256, 256, 0, stream>>>(
      deg_g, kNCAT + 256, psrc_g + kE, psrc_s + kE);

  prep<<<7195, 256, 0, stream>>>(
      x_sample, x_gene, Wl1_sg, Wr1_gs, sl1_W, Wr1_sg, Wl1_gs, Wl3, Wr3, sl3_W,
      bl1_sg, br1_gs, sl1_b, br1_sg, bl1_gs, br3, sl3_b,
      sg_dst, gs_dst, deg_g, deg_s,
      xs_bf, xg_bf, Wt1, Wt2, Wt3, Wt4, bc1, bc2, bc4);

  scan_fused<<<kNB, 256, 0, stream>>>(deg_g, rp_g, rp_s, pval, pflag);

  // layer-1: build (1024) + GEMM0 (288) + GEMM1 (1280), XCD-swizzled GEMM tiles
  gemm_build<<<1024 + 288 + 1280, 256, 0, stream>>>(
      1024,
      xs_bf, Wt1, bc1, cat1, kNS, 576, 288, 9, 4,
      xg_bf, Wt2, bc2, cat2, kNG, 512, 8, 20,
      sg_dst, sg_src, rp_g, deg_g, psrc_g,
      gs_dst, gs_src, rp_s, deg_s, psrc_s);

  // stage 2 (1024 blocks, heavy, FIRST) + stage 1 (2500 blocks)
  gat12<<<1024 + 2500, 256, 0, stream>>>(
      cat1, cat2, 512, att1_sg, psrc_g, rp_g, bias1_sg, xg1_bf, kNG,
      cat2 + 256, cat1 + 256, 576, att1_gs, psrc_s, rp_s, bias1_gs,
      cat1 + 512, 576, xs1_bf, kNS, 1024);

  // layer-3: GEMM0 (1280) + GEMM1 (320), no build region
  gemm_build<<<1280 + 320, 256, 0, stream>>>(
      0,
      xg1_bf, Wt3, bl3, xl3, kNG, 512, 1280, 8, 20,
      xs1_bf, Wt4, bc4, cat4, kNS, 640, 10, 4,
      sg_dst, sg_src, rp_g, deg_g, psrc_g,
      gs_dst, gs_src, rp_s, deg_s, psrc_s);

  // stage 3: 2 waves per dst (2048 blocks)
  gat3<<<kNS / 2, 256, 0, stream>>>(
      xl3, cat4, att3, psrc_s, rp_s, bias3, cat4 + 512, (float*)d_out);
}

// Round 15
// 145.344 us; speedup vs baseline: 1.0666x; 1.0666x over previous
//
#include <hip/hip_runtime.h>
#include <hip/hip_bf16.h>
#include <cstdint>

constexpr int kNS = 4096;
constexpr int kNG = 20000;
constexpr int kE  = 131072;
constexpr int kNCAT = kNG + kNS;          // 24096
constexpr int kNB = (kNCAT + 255) / 256;  // 95 scan blocks
constexpr float kL2E = 1.4426950408889634f;

typedef __attribute__((ext_vector_type(8))) short short8;
typedef __attribute__((ext_vector_type(4))) float f32x4;
typedef __attribute__((ext_vector_type(2))) float f32x2;

__device__ __forceinline__ float elu_f(float v) { return v > 0.f ? v : expm1f(v); }

__device__ __forceinline__ unsigned short f2bf(float f) {
  union { float f; unsigned u; } v; v.f = f;
  unsigned r = v.u + 0x7FFF + ((v.u >> 16) & 1);
  return (unsigned short)(r >> 16);
}

__device__ __forceinline__ float bf2f(unsigned short u) {
  union { unsigned u; float f; } v; v.u = ((unsigned)u) << 16; return v.f;
}

// unpack 2 bf16 (packed in a dword) -> f32x2 {lo, hi}
__device__ __forceinline__ f32x2 bfp2(unsigned u) {
  union { unsigned u; float f; } lo, hi;
  lo.u = u << 16; hi.u = u & 0xffff0000u;
  return (f32x2){lo.f, hi.f};
}

// ================= zero kernel (deg|pval|pflag region + psrc pads) ====
__global__ __launch_bounds__(256) void zero_int(int* __restrict__ p, int n,
                                                int* __restrict__ padA,
                                                int* __restrict__ padB) {
  int i = blockIdx.x * 256 + threadIdx.x;
  if (i < n) p[i] = 0;
  if (blockIdx.x == 0 && threadIdx.x < 16) {
    padA[threadIdx.x] = 0;
    padB[threadIdx.x] = 0;
  }
}

// ================= prep: conversions / LDS-tiled W transpose / bias / histogram ========
__global__ __launch_bounds__(256) void prep(
    const float* __restrict__ xs, const float* __restrict__ xg,
    const float* __restrict__ Wl1_sg, const float* __restrict__ Wr1_gs,
    const float* __restrict__ sl1_W, const float* __restrict__ Wr1_sg,
    const float* __restrict__ Wl1_gs, const float* __restrict__ Wl3,
    const float* __restrict__ Wr3, const float* __restrict__ sl3_W,
    const float* __restrict__ bl1_sg, const float* __restrict__ br1_gs,
    const float* __restrict__ sl1_b, const float* __restrict__ br1_sg,
    const float* __restrict__ bl1_gs, const float* __restrict__ br3,
    const float* __restrict__ sl3_b,
    const int* __restrict__ sg_dst, const int* __restrict__ gs_dst,
    int* __restrict__ deg_g, int* __restrict__ deg_s,
    unsigned short* __restrict__ xs_bf, unsigned short* __restrict__ xg_bf,
    unsigned short* __restrict__ Wt1, unsigned short* __restrict__ Wt2,
    unsigned short* __restrict__ Wt3, unsigned short* __restrict__ Wt4,
    float* __restrict__ bc1, float* __restrict__ bc2, float* __restrict__ bc4) {
  __shared__ float tile[64][65];
  int bid = blockIdx.x, tid = threadIdx.x;
  if (bid < 1024) {
    int i = (bid * 256 + tid) * 4;
    float4 v = *(const float4*)&xs[i];
    ushort4 o = {f2bf(v.x), f2bf(v.y), f2bf(v.z), f2bf(v.w)};
    *(ushort4*)&xs_bf[i] = o;
    return;
  }
  bid -= 1024;
  if (bid < 5000) {
    int i = (bid * 256 + tid) * 4;
    float4 v = *(const float4*)&xg[i];
    ushort4 o = {f2bf(v.x), f2bf(v.y), f2bf(v.z), f2bf(v.w)};
    *(ushort4*)&xg_bf[i] = o;
    return;
  }
  bid -= 5000;
  auto wtile = [&](const float* W, unsigned short* Wt, int N, int b) {
    int ntn = N >> 6;
    int tn = b % ntn, tk = b / ntn;
    int c = tid & 63, rb = tid >> 6;
#pragma unroll
    for (int w = 0; w < 16; ++w) {
      int r = rb + w * 4;
      tile[r][c] = W[(size_t)(tk * 64 + r) * N + tn * 64 + c];
    }
    __syncthreads();
#pragma unroll
    for (int w = 0; w < 16; ++w) {
      int n = rb + w * 4;
      Wt[(size_t)(tn * 64 + n) * 256 + tk * 64 + c] = f2bf(tile[c][n]);
    }
  };
  if (bid < 36) {               // Wt1 = [Wl1_sg | Wr1_gs | sl1_W], N=576
    int ntn = 9, tn = bid % ntn, tk = bid / ntn;
    int c = tid & 63, rb = tid >> 6;
    int ncol = tn * 64;
#pragma unroll
    for (int w = 0; w < 16; ++w) {
      int r = rb + w * 4;
      int col = ncol + c;
      float v;
      if (col < 256) v = Wl1_sg[(size_t)(tk * 64 + r) * 256 + col];
      else if (col < 512) v = Wr1_gs[(size_t)(tk * 64 + r) * 256 + (col - 256)];
      else v = sl1_W[(size_t)(tk * 64 + r) * 64 + (col - 512)];
      tile[r][c] = v;
    }
    __syncthreads();
#pragma unroll
    for (int w = 0; w < 16; ++w) {
      int n = rb + w * 4;
      Wt1[(size_t)(ncol + n) * 256 + tk * 64 + c] = f2bf(tile[c][n]);
    }
    return;
  }
  bid -= 36;
  if (bid < 32) {               // Wt2 = [Wr1_sg | Wl1_gs], N=512
    int ntn = 8, tn = bid % ntn, tk = bid / ntn;
    int c = tid & 63, rb = tid >> 6;
    int ncol = tn * 64;
#pragma unroll
    for (int w = 0; w < 16; ++w) {
      int r = rb + w * 4;
      int col = ncol + c;
      float v = col < 256 ? Wr1_sg[(size_t)(tk * 64 + r) * 256 + col]
                          : Wl1_gs[(size_t)(tk * 64 + r) * 256 + (col - 256)];
      tile[r][c] = v;
    }
    __syncthreads();
#pragma unroll
    for (int w = 0; w < 16; ++w) {
      int n = rb + w * 4;
      Wt2[(size_t)(ncol + n) * 256 + tk * 64 + c] = f2bf(tile[c][n]);
    }
    return;
  }
  bid -= 32;
  if (bid < 32) { wtile(Wl3, Wt3, 512, bid); return; }
  bid -= 32;
  if (bid < 40) {               // Wt4 = [Wr3 | sl3_W], N=640
    int ntn = 10, tn = bid % ntn, tk = bid / ntn;
    int c = tid & 63, rb = tid >> 6;
    int ncol = tn * 64;
#pragma unroll
    for (int w = 0; w < 16; ++w) {
      int r = rb + w * 4;
      int col = ncol + c;
      float v = col < 512 ? Wr3[(size_t)(tk * 64 + r) * 512 + col]
                          : sl3_W[(size_t)(tk * 64 + r) * 128 + (col - 512)];
      tile[r][c] = v;
    }
    __syncthreads();
#pragma unroll
    for (int w = 0; w < 16; ++w) {
      int n = rb + w * 4;
      Wt4[(size_t)(ncol + n) * 256 + tk * 64 + c] = f2bf(tile[c][n]);
    }
    return;
  }
  bid -= 40;
  if (bid < 7) {
    int j = bid * 256 + tid;
    if (j < 256) bc1[j] = bl1_sg[j];
    else if (j < 512) bc1[j] = br1_gs[j - 256];
    else if (j < 576) bc1[j] = sl1_b[j - 512];
    else if (j < 832) bc2[j - 576] = br1_sg[j - 576];
    else if (j < 1088) bc2[j - 576] = bl1_gs[j - 832];
    else if (j < 1600) bc4[j - 1088] = br3[j - 1088];
    else if (j < 1728) bc4[j - 1088] = sl3_b[j - 1600];
    return;
  }
  bid -= 7;
  int i = bid * 256 + tid;
  if (i < kE) atomicAdd(&deg_g[sg_dst[i]], 1);
  else atomicAdd(&deg_s[gs_dst[i - kE]], 1);
}

// ================= single-dispatch scan with decoupled lookback =================
__global__ __launch_bounds__(256) void scan_fused(
    int* __restrict__ deg, int* __restrict__ rp_g, int* __restrict__ rp_s,
    int* __restrict__ pval, int* __restrict__ pflag) {
  int b = blockIdx.x, t = threadIdx.x;
  int i = b * 256 + t;
  int v = i < kNCAT ? deg[i] : 0;
  __shared__ int s[256];
  s[t] = v;
  __syncthreads();
  for (int ofs = 1; ofs < 256; ofs <<= 1) {
    int add = t >= ofs ? s[t - ofs] : 0;
    __syncthreads();
    s[t] += add;
    __syncthreads();
  }
  if (t == 255) {
    atomicExch(&pval[b], s[255]);
    __threadfence();
    atomicExch(&pflag[b], 1);
  }
  int pre = 0;
  if (t < b) {
    while (atomicAdd(&pflag[t], 0) == 0) {}
    pre = atomicAdd(&pval[t], 0);
  }
  pre += __shfl_xor(pre, 1);  pre += __shfl_xor(pre, 2);
  pre += __shfl_xor(pre, 4);  pre += __shfl_xor(pre, 8);
  pre += __shfl_xor(pre, 16); pre += __shfl_xor(pre, 32);
  __shared__ int ws4[4];
  if ((t & 63) == 0) ws4[t >> 6] = pre;
  __syncthreads();
  int prefix = ws4[0] + ws4[1] + ws4[2] + ws4[3];
  int ex = prefix + s[t] - v;
  if (i < kNG) { rp_g[i] = ex; deg[i] = 0; }
  else if (i < kNCAT) { rp_s[i - kNG] = ex - kE; deg[i] = 0; }
  if (b == 0 && t == 0) { rp_g[kNG] = kE; rp_s[kNS] = kE; }
}

// ================= MFMA GEMM body (128x64 tile, BK=32, K=256) =================
__device__ __forceinline__ void gemm_body(
    const unsigned short* __restrict__ A, const unsigned short* __restrict__ Bt,
    const float* __restrict__ bias, unsigned short* __restrict__ Cb,
    int M, int N, int bx, int by) {
  __shared__ alignas(16) unsigned short As[128 * 32];
  __shared__ alignas(16) unsigned short Bs[64 * 32];
  const int tid = threadIdx.x;
  const int wave = tid >> 6, lane = tid & 63;
  const int brow = by * 128, bcol = bx * 64;
  const int wrow = (wave >> 1) * 64, wcol = (wave & 1) * 32;
  const int la = lane & 15, lk = (lane >> 4) * 8;
  f32x4 acc[4][2] = {};
  for (int k0 = 0; k0 < 256; k0 += 32) {
#pragma unroll
    for (int c = 0; c < 2; ++c) {
      int seg = wave * 128 + c * 64 + lane;
      int row = seg >> 2, ks = (seg & 3) * 8;
      int grow = brow + row; if (grow > M - 1) grow = M - 1;
      const unsigned short* g = A + (size_t)grow * 256 + k0 + ks;
      __builtin_amdgcn_global_load_lds(
          (const __attribute__((address_space(1))) unsigned*)g,
          (__attribute__((address_space(3))) unsigned*)&As[(wave * 128 + c * 64) * 8],
          16, 0, 0);
    }
    {
      int seg = wave * 64 + lane;
      int row = seg >> 2, ks = (seg & 3) * 8;
      const unsigned short* g = Bt + (size_t)(bcol + row) * 256 + k0 + ks;
      __builtin_amdgcn_global_load_lds(
          (const __attribute__((address_space(1))) unsigned*)g,
          (__attribute__((address_space(3))) unsigned*)&Bs[(wave * 64) * 8],
          16, 0, 0);
    }
    __syncthreads();
    short8 bfr[2];
#pragma unroll
    for (int ni = 0; ni < 2; ++ni)
      bfr[ni] = *(const short8*)&Bs[(wcol + ni * 16 + la) * 32 + lk];
#pragma unroll
    for (int mi = 0; mi < 4; ++mi) {
      short8 af = *(const short8*)&As[(wrow + mi * 16 + la) * 32 + lk];
#pragma unroll
      for (int ni = 0; ni < 2; ++ni)
        acc[mi][ni] = __builtin_amdgcn_mfma_f32_16x16x32_bf16(af, bfr[ni], acc[mi][ni], 0, 0, 0);
    }
    __syncthreads();
  }
  const int r0 = (lane >> 4) * 4;
#pragma unroll
  for (int mi = 0; mi < 4; ++mi) {
#pragma unroll
    for (int r = 0; r < 4; ++r) {
      int row = brow + wrow + mi * 16 + r0 + r;
      if (row >= M) continue;
#pragma unroll
      for (int ni = 0; ni < 2; ++ni) {
        int col = bcol + wcol + ni * 16 + la;
        Cb[(size_t)row * N + col] = f2bf(acc[mi][ni][r] + bias[col]);
      }
    }
  }
}

// XCD-aware tile decode (T1): contiguous by-range per XCD so A-panels live in ONE L2.
__device__ __forceinline__ void gemm_swz(
    const unsigned short* A, const unsigned short* Bt, const float* bias,
    unsigned short* Cb, int M, int N, int flat, int nbx, int rows_per_xcd) {
  int x = flat & 7, k = flat >> 3;
  int by = x * rows_per_xcd + k / nbx;
  int bx = k % nbx;
  if (by * 128 >= M) return;
  gemm_body(A, Bt, bias, Cb, M, N, bx, by);
}

// two GEMMs + (optionally) CSR perm-build (stores PRE-SCALED row offsets) in one dispatch
__global__ __launch_bounds__(256) void gemm_build(
    const unsigned short* __restrict__ A0, const unsigned short* __restrict__ B0,
    const float* __restrict__ b0, unsigned short* __restrict__ C0, int M0, int N0,
    int nb0, int nbx0, int rpx0,
    const unsigned short* __restrict__ A1, const unsigned short* __restrict__ B1,
    const float* __restrict__ b1, unsigned short* __restrict__ C1, int M1, int N1,
    int nb1, int nbx1, int rpx1,
    const int* __restrict__ sgd, const int* __restrict__ sgs,
    const int* __restrict__ rpg, int* __restrict__ curg, int* __restrict__ psg,
    const int* __restrict__ gsd, const int* __restrict__ gss,
    const int* __restrict__ rps, int* __restrict__ curs, int* __restrict__ pss) {
  int flat = blockIdx.x;
  if (flat < nb0) {
    gemm_swz(A0, B0, b0, C0, M0, N0, flat, nbx0, rpx0);
    return;
  }
  flat -= nb0;
  if (flat < nb1) {
    gemm_swz(A1, B1, b1, C1, M1, N1, flat, nbx1, rpx1);
    return;
  }
  flat -= nb1;
  int i = flat * 256 + threadIdx.x;
  if (i < kE) {
    int d = sgd[i];
    psg[rpg[d] + atomicAdd(&curg[d], 1)] = sgs[i] * 576;   // stage-1 xl ld = 576
  } else {
    i -= kE;
    int d = gsd[i];
    pss[rps[d] + atomicAdd(&curs[d], 1)] = gss[i] * 512;   // stage-2/3 xl ld = 512
  }
}

// ================= fused GATv2, C=64, no-max softmax, batch-4 + psrc prefetch =========
// psrc padded with >=16 zeros; over-reads hit next dst's valid offsets or the pad.
template <bool SPLIT, bool ADDSL>
__device__ __forceinline__ void gat64_body(
    const unsigned short* __restrict__ xl,
    const unsigned short* __restrict__ xr, int ldr,
    const float* __restrict__ att,
    const int* __restrict__ psrc, const int* __restrict__ rp,
    const float* __restrict__ bias,
    const unsigned short* __restrict__ sl, int ldsl,
    unsigned short* __restrict__ out, int N, int rbid) {
  int tid = threadIdx.x;
  int cl = tid & 31;
  int d, sub;
  if (SPLIT) { d = rbid * 4 + (tid >> 6); sub = (tid >> 5) & 1; }
  else       { d = rbid * 8 + (tid >> 5); sub = 0; }
  if (d >= N) return;
  const unsigned short* xlb = xl + cl * 8;
  f32x2 xr2[4], at2[4];
  {
    const uint4 xu = *(const uint4*)&xr[(size_t)d * ldr + cl * 8];
    xr2[0] = bfp2(xu.x); xr2[1] = bfp2(xu.y); xr2[2] = bfp2(xu.z); xr2[3] = bfp2(xu.w);
    float4 a0 = *(const float4*)&att[cl * 8];
    float4 a1 = *(const float4*)&att[cl * 8 + 4];
    at2[0] = (f32x2){a0.x, a0.y} * kL2E; at2[1] = (f32x2){a0.z, a0.w} * kL2E;
    at2[2] = (f32x2){a1.x, a1.y} * kL2E; at2[3] = (f32x2){a1.z, a1.w} * kL2E;
  }
  float l = 0.f;
  f32x2 acc2[4] = {};
  int i0 = rp[d], i1 = rp[d + 1];
  constexpr int STRIDE = SPLIT ? 8 : 4;
  int i = SPLIT ? i0 + sub * 4 : i0;
  // preload first batch indices (rotated software pipeline)
  int o0 = psrc[i], o1 = psrc[i + 1], o2 = psrc[i + 2], o3 = psrc[i + 3];
  for (; i < i1; i += STRIDE) {
    int nx = i + STRIDE;
    int p0 = psrc[nx], p1 = psrc[nx + 1], p2 = psrc[nx + 2], p3 = psrc[nx + 3];
    uint4 xu0 = *(const uint4*)&xlb[o0];
    uint4 xu1 = *(const uint4*)&xlb[o1];
    uint4 xu2 = *(const uint4*)&xlb[o2];
    uint4 xu3 = *(const uint4*)&xlb[o3];
    f32x2 xf[4][4];
    xf[0][0] = bfp2(xu0.x); xf[0][1] = bfp2(xu0.y); xf[0][2] = bfp2(xu0.z); xf[0][3] = bfp2(xu0.w);
    xf[1][0] = bfp2(xu1.x); xf[1][1] = bfp2(xu1.y); xf[1][2] = bfp2(xu1.z); xf[1][3] = bfp2(xu1.w);
    xf[2][0] = bfp2(xu2.x); xf[2][1] = bfp2(xu2.y); xf[2][2] = bfp2(xu2.z); xf[2][3] = bfp2(xu2.w);
    xf[3][0] = bfp2(xu3.x); xf[3][1] = bfp2(xu3.y); xf[3][2] = bfp2(xu3.z); xf[3][3] = bfp2(xu3.w);
    float dt[4];
#pragma unroll
    for (int b = 0; b < 4; ++b) {
      f32x2 d2 = {0.f, 0.f};
#pragma unroll
      for (int p = 0; p < 4; ++p) {
        f32x2 v = xf[b][p] + xr2[p];
        f32x2 lk = __builtin_elementwise_max(v, v * 0.2f);
        d2 = __builtin_elementwise_fma(lk, at2[p], d2);
      }
      float dd = d2.x + d2.y;
      dd += __shfl_xor(dd, 1);
      dd += __shfl_xor(dd, 2);
      dd += __shfl_xor(dd, 4);   // 8-lane head reduce
      dt[b] = dd;
    }
    float w0 = __builtin_amdgcn_exp2f(dt[0]);
    float w1 = (i + 1 < i1) ? __builtin_amdgcn_exp2f(dt[1]) : 0.f;
    float w2 = (i + 2 < i1) ? __builtin_amdgcn_exp2f(dt[2]) : 0.f;
    float w3 = (i + 3 < i1) ? __builtin_amdgcn_exp2f(dt[3]) : 0.f;
    l += (w0 + w1) + (w2 + w3);
#pragma unroll
    for (int p = 0; p < 4; ++p) {
      acc2[p] = __builtin_elementwise_fma(xf[0][p], (f32x2){w0, w0}, acc2[p]);
      acc2[p] = __builtin_elementwise_fma(xf[1][p], (f32x2){w1, w1}, acc2[p]);
      acc2[p] = __builtin_elementwise_fma(xf[2][p], (f32x2){w2, w2}, acc2[p]);
      acc2[p] = __builtin_elementwise_fma(xf[3][p], (f32x2){w3, w3}, acc2[p]);
    }
    o0 = p0; o1 = p1; o2 = p2; o3 = p3;
  }
  if (SPLIT) {
    l += __shfl_xor(l, 32);
#pragma unroll
    for (int p = 0; p < 4; ++p) {
      acc2[p].x += __shfl_xor(acc2[p].x, 32);
      acc2[p].y += __shfl_xor(acc2[p].y, 32);
    }
    if (sub != 0) return;
  }
  float dinv = __builtin_amdgcn_rcpf(l + 1e-16f);
  short8 o;
#pragma unroll
  for (int p = 0; p < 4; ++p) {
    int c = cl * 8 + p * 2;
    float v0 = acc2[p].x * dinv + bias[c];
    float v1 = acc2[p].y * dinv + bias[c + 1];
    if (ADDSL) {
      v0 += bf2f(sl[(size_t)d * ldsl + (c & 63)]);
      v1 += bf2f(sl[(size_t)d * ldsl + ((c + 1) & 63)]);
    }
    o[p * 2]     = (short)f2bf(elu_f(v0));
    o[p * 2 + 1] = (short)f2bf(elu_f(v1));
  }
  *(short8*)&out[(size_t)d * 256 + cl * 8] = o;
}

// stage2 (split, heavy deg~32) FIRST so the dispatch tail drains on cheap stage-1 blocks
__global__ __launch_bounds__(256) void gat12(
    const unsigned short* __restrict__ xlA,
    const unsigned short* __restrict__ xrA, int ldrA,
    const float* __restrict__ attA, const int* __restrict__ psA,
    const int* __restrict__ rpA, const float* __restrict__ biasA,
    unsigned short* __restrict__ outA, int NA,
    const unsigned short* __restrict__ xlB,
    const unsigned short* __restrict__ xrB, int ldrB,
    const float* __restrict__ attB, const int* __restrict__ psB,
    const int* __restrict__ rpB, const float* __restrict__ biasB,
    const unsigned short* __restrict__ slB, int ldslB,
    unsigned short* __restrict__ outB, int NB, int nbB) {
  int bid = blockIdx.x;
  if (bid < nbB)
    gat64_body<true, true>(xlB, xrB, ldrB, attB, psB, rpB, biasB,
                           slB, ldslB, outB, NB, bid);
  else
    gat64_body<false, false>(xlA, xrA, ldrA, attA, psA, rpA, biasA,
                             nullptr, 0, outA, NA, bid - nbB);
}

// ================= stage-3 GAT, C=128: 2 waves/dst, batch-4 + prefetch, head-mean =====
__global__ __launch_bounds__(256) void gat3(
    const unsigned short* __restrict__ xl,   // [NG,512] (offsets pre-scaled by 512)
    const unsigned short* __restrict__ xr,   // cat4 [NS,640], cols 0..511
    const float* __restrict__ att,
    const int* __restrict__ psrc, const int* __restrict__ rp,
    const float* __restrict__ bias,
    const unsigned short* __restrict__ sl,   // cat4 cols 512..639
    float* __restrict__ out) {
  __shared__ float sm_acc[2][64][8];
  __shared__ float sm_l[2][64];
  int w = threadIdx.x >> 6, lane = threadIdx.x & 63;
  int p = w >> 1, wp = w & 1;
  int d = blockIdx.x * 2 + p;
  const unsigned short* xlb = xl + lane * 8;
  f32x2 xr2[4], at2[4];
  {
    const uint4 xu = *(const uint4*)&xr[(size_t)d * 640 + lane * 8];
    xr2[0] = bfp2(xu.x); xr2[1] = bfp2(xu.y); xr2[2] = bfp2(xu.z); xr2[3] = bfp2(xu.w);
    float4 a0 = *(const float4*)&att[lane * 8];
    float4 a1 = *(const float4*)&att[lane * 8 + 4];
    at2[0] = (f32x2){a0.x, a0.y} * kL2E; at2[1] = (f32x2){a0.z, a0.w} * kL2E;
    at2[2] = (f32x2){a1.x, a1.y} * kL2E; at2[3] = (f32x2){a1.z, a1.w} * kL2E;
  }
  float l = 0.f;
  f32x2 acc2[4] = {};
  int i0 = rp[d], i1 = rp[d + 1];
  int i = i0 + wp * 4;
  int o0 = psrc[i], o1 = psrc[i + 1], o2 = psrc[i + 2], o3 = psrc[i + 3];
  for (; i < i1; i += 8) {
    int nx = i + 8;
    int p0 = psrc[nx], p1 = psrc[nx + 1], p2 = psrc[nx + 2], p3 = psrc[nx + 3];
    uint4 xu0 = *(const uint4*)&xlb[o0];
    uint4 xu1 = *(const uint4*)&xlb[o1];
    uint4 xu2 = *(const uint4*)&xlb[o2];
    uint4 xu3 = *(const uint4*)&xlb[o3];
    f32x2 xf[4][4];
    xf[0][0] = bfp2(xu0.x); xf[0][1] = bfp2(xu0.y); xf[0][2] = bfp2(xu0.z); xf[0][3] = bfp2(xu0.w);
    xf[1][0] = bfp2(xu1.x); xf[1][1] = bfp2(xu1.y); xf[1][2] = bfp2(xu1.z); xf[1][3] = bfp2(xu1.w);
    xf[2][0] = bfp2(xu2.x); xf[2][1] = bfp2(xu2.y); xf[2][2] = bfp2(xu2.z); xf[2][3] = bfp2(xu2.w);
    xf[3][0] = bfp2(xu3.x); xf[3][1] = bfp2(xu3.y); xf[3][2] = bfp2(xu3.z); xf[3][3] = bfp2(xu3.w);
    float dt[4];
#pragma unroll
    for (int b = 0; b < 4; ++b) {
      f32x2 d2 = {0.f, 0.f};
#pragma unroll
      for (int q = 0; q < 4; ++q) {
        f32x2 v = xf[b][q] + xr2[q];
        f32x2 lk = __builtin_elementwise_max(v, v * 0.2f);
        d2 = __builtin_elementwise_fma(lk, at2[q], d2);
      }
      float dd = d2.x + d2.y;
      dd += __shfl_xor(dd, 1);
      dd += __shfl_xor(dd, 2);
      dd += __shfl_xor(dd, 4);
      dd += __shfl_xor(dd, 8);   // 16-lane head reduce (C=128)
      dt[b] = dd;
    }
    float w0 = __builtin_amdgcn_exp2f(dt[0]);
    float w1 = (i + 1 < i1) ? __builtin_amdgcn_exp2f(dt[1]) : 0.f;
    float w2 = (i + 2 < i1) ? __builtin_amdgcn_exp2f(dt[2]) : 0.f;
    float w3 = (i + 3 < i1) ? __builtin_amdgcn_exp2f(dt[3]) : 0.f;
    l += (w0 + w1) + (w2 + w3);
#pragma unroll
    for (int q = 0; q < 4; ++q) {
      acc2[q] = __builtin_elementwise_fma(xf[0][q], (f32x2){w0, w0}, acc2[q]);
      acc2[q] = __builtin_elementwise_fma(xf[1][q], (f32x2){w1, w1}, acc2[q]);
      acc2[q] = __builtin_elementwise_fma(xf[2][q], (f32x2){w2, w2}, acc2[q]);
      acc2[q] = __builtin_elementwise_fma(xf[3][q], (f32x2){w3, w3}, acc2[q]);
    }
    o0 = p0; o1 = p1; o2 = p2; o3 = p3;
  }
  if (wp == 1) {
#pragma unroll
    for (int q = 0; q < 4; ++q) {
      sm_acc[p][lane][q * 2]     = acc2[q].x;
      sm_acc[p][lane][q * 2 + 1] = acc2[q].y;
    }
    sm_l[p][lane] = l;
  }
  __syncthreads();
  if (wp == 0) {
    l += sm_l[p][lane];
    float dinv = __builtin_amdgcn_rcpf(l + 1e-16f);
    float r[8];
#pragma unroll
    for (int q = 0; q < 4; ++q) {
      r[q * 2]     = (acc2[q].x + sm_acc[p][lane][q * 2]) * dinv;
      r[q * 2 + 1] = (acc2[q].y + sm_acc[p][lane][q * 2 + 1]) * dinv;
    }
#pragma unroll
    for (int j = 0; j < 8; ++j) {
      r[j] += __shfl_xor(r[j], 16);
      r[j] += __shfl_xor(r[j], 32);
    }
    if (lane < 16) {
#pragma unroll
      for (int j = 0; j < 8; ++j) {
        int c = lane * 8 + j;
        out[(size_t)d * 128 + c] =
            elu_f(0.25f * r[j] + bias[c] + bf2f(sl[(size_t)d * 640 + c]));
      }
    }
  }
}

extern "C" void kernel_launch(void* const* d_in, const int* in_sizes, int n_in,
                              void* d_out, int out_size, void* d_ws, size_t ws_size,
                              hipStream_t stream) {
  const float* x_sample = (const float*)d_in[0];
  const float* x_gene   = (const float*)d_in[1];
  const int* sg_src = (const int*)d_in[2];
  const int* sg_dst = (const int*)d_in[3];
  const int* gs_src = (const int*)d_in[4];
  const int* gs_dst = (const int*)d_in[5];
  const float* Wl1_sg = (const float*)d_in[6];
  const float* bl1_sg = (const float*)d_in[7];
  const float* Wr1_sg = (const float*)d_in[8];
  const float* br1_sg = (const float*)d_in[9];
  const float* att1_sg = (const float*)d_in[10];
  const float* bias1_sg = (const float*)d_in[11];
  const float* Wl1_gs = (const float*)d_in[12];
  const float* bl1_gs = (const float*)d_in[13];
  const float* Wr1_gs = (const float*)d_in[14];
  const float* br1_gs = (const float*)d_in[15];
  const float* att1_gs = (const float*)d_in[16];
  const float* bias1_gs = (const float*)d_in[17];
  const float* Wl3 = (const float*)d_in[18];
  const float* bl3 = (const float*)d_in[19];
  const float* Wr3 = (const float*)d_in[20];
  const float* br3 = (const float*)d_in[21];
  const float* att3 = (const float*)d_in[22];
  const float* bias3 = (const float*)d_in[23];
  const float* sl1_W = (const float*)d_in[24];
  const float* sl1_b = (const float*)d_in[25];
  const float* sl3_W = (const float*)d_in[26];
  const float* sl3_b = (const float*)d_in[27];

  float* ws = (float*)d_ws;
  size_t off = 0;
  auto alloc = [&](size_t n) { float* p = ws + off; off += n; return p; };
  float* bc1 = alloc(576);
  float* bc2 = alloc(512);
  float* bc4 = alloc(640);
  unsigned short* cat1 = (unsigned short*)alloc((size_t)kNS * 576 / 2);  // xl_sg|xr_gs|sl1o
  unsigned short* cat2 = (unsigned short*)alloc((size_t)kNG * 512 / 2);  // xr_sg|xl_gs
  unsigned short* xl3  = (unsigned short*)alloc((size_t)kNG * 512 / 2);
  unsigned short* cat4 = (unsigned short*)alloc((size_t)kNS * 640 / 2);  // xr3|sl3o
  unsigned short* xs_bf  = (unsigned short*)alloc((size_t)kNS * 256 / 2);
  unsigned short* xg_bf  = (unsigned short*)alloc((size_t)kNG * 256 / 2);
  unsigned short* xg1_bf = (unsigned short*)alloc((size_t)kNG * 256 / 2);
  unsigned short* xs1_bf = (unsigned short*)alloc((size_t)kNS * 256 / 2);
  unsigned short* Wt1 = (unsigned short*)alloc(576 * 256 / 2);
  unsigned short* Wt2 = (unsigned short*)alloc(512 * 256 / 2);
  unsigned short* Wt3 = (unsigned short*)alloc(512 * 256 / 2);
  unsigned short* Wt4 = (unsigned short*)alloc(640 * 256 / 2);
  int* deg_g  = (int*)alloc(kNG);   // deg_g|deg_s|pval|pflag contiguous for one zero pass
  int* deg_s  = (int*)alloc(kNS);
  int* pval   = (int*)alloc(128);
  int* pflag  = (int*)alloc(128);
  int* rp_g   = (int*)alloc(kNG + 1);
  int* rp_s   = (int*)alloc(kNS + 1);
  int* psrc_g = (int*)alloc(kE + 16);  // +16 pad (zeroed) for prefetch over-reads
  int* psrc_s = (int*)alloc(kE + 16);

  zero_int<<<(kNCAT + 256 + 255) / 256, 256, 0, stream>>>(
      deg_g, kNCAT + 256, psrc_g + kE, psrc_s + kE);

  prep<<<7195, 256, 0, stream>>>(
      x_sample, x_gene, Wl1_sg, Wr1_gs, sl1_W, Wr1_sg, Wl1_gs, Wl3, Wr3, sl3_W,
      bl1_sg, br1_gs, sl1_b, br1_sg, bl1_gs, br3, sl3_b,
      sg_dst, gs_dst, deg_g, deg_s,
      xs_bf, xg_bf, Wt1, Wt2, Wt3, Wt4, bc1, bc2, bc4);

  scan_fused<<<kNB, 256, 0, stream>>>(deg_g, rp_g, rp_s, pval, pflag);

  // layer-1 GEMMs (XCD-swizzled tiles) + CSR perm build.
  gemm_build<<<288 + 1280 + 1024, 256, 0, stream>>>(
      xs_bf, Wt1, bc1, cat1, kNS, 576, 288, 9, 4,
      xg_bf, Wt2, bc2, cat2, kNG, 512, 1280, 8, 20,
      sg_dst, sg_src, rp_g, deg_g, psrc_g,
      gs_dst, gs_src, rp_s, deg_s, psrc_s);

  // stage 2 (1024 blocks, heavy, FIRST) + stage 1 (2500 blocks, cheap tail)
  gat12<<<1024 + 2500, 256, 0, stream>>>(
      cat1, cat2, 512, att1_sg, psrc_g, rp_g, bias1_sg, xg1_bf, kNG,
      cat2 + 256, cat1 + 256, 576, att1_gs, psrc_s, rp_s, bias1_gs,
      cat1 + 512, 576, xs1_bf, kNS, 1024);

  // layer-3 GEMMs (XCD-swizzled).
  gemm_build<<<1280 + 320, 256, 0, stream>>>(
      xg1_bf, Wt3, bl3, xl3, kNG, 512, 1280, 8, 20,
      xs1_bf, Wt4, bc4, cat4, kNS, 640, 320, 10, 4,
      sg_dst, sg_src, rp_g, deg_g, psrc_g,
      gs_dst, gs_src, rp_s, deg_s, psrc_s);

  // stage 3: 2 waves per dst (2048 blocks)
  gat3<<<kNS / 2, 256, 0, stream>>>(
      xl3, cat4, att3, psrc_s, rp_s, bias3, cat4 + 512, (float*)d_out);
}